// Round 9
// baseline (462.928 us; speedup 1.0000x reference)
//
#include <hip/hip_runtime.h>
#include <math.h>

// Problem constants (from reference setup_inputs): B_eff=32, T=2048, D=1024, S=4.
#define NSTREAMS 4
#define SINKHORN_ITERS 10
#define TAU 0.05f
#define BATCH 8            // B_eff / S
#define N4_SHIFT 19        // T*D/4 = 524288 float4 per (b,stream) slice

typedef float f32x4 __attribute__((ext_vector_type(4)));

// ---------------------------------------------------------------------------
// Single fused kernel. R6 change: NO nontemporal loads/stores — plain cached
// accesses, matching the 6.29 TB/s float4-copy recipe (m13) and the 6.5 TB/s
// harness fills. NT bypassed L2 and appears to cap streaming BW (~3.4 TB/s).
// Prologue: lanes 0-3 of wave 0 run Sinkhorn 4-wide (u/v via __shfl);
// lane 64 (wave 1) runs the two softmaxes concurrently.
// Grid covers one b-slice exactly: 2048 blocks * 256 thr = 1<<19 float4 items;
// compile-time loop over b = 0..7.
// ---------------------------------------------------------------------------
__global__ __launch_bounds__(256) void fused_mix_kernel(
    const f32x4* __restrict__ in,
    f32x4* __restrict__ out,
    const float* __restrict__ res_logits,
    const float* __restrict__ pre_logits,
    const float* __restrict__ post_logits)
{
    __shared__ float sc[24];   // [0:16) h_res row-major, [16:20) h_pre, [20:24) h_post

    const int tid = threadIdx.x;

    if (tid < 4) {
        const int l = tid;
        // lane l holds row l (for u-step) and column l (for v-step) of scaled.
        float row[4], col[4];
        float mx = -INFINITY;
        #pragma unroll
        for (int j = 0; j < 4; ++j) {
            row[j] = res_logits[l * 4 + j] * (1.0f / TAU);
            mx = fmaxf(mx, row[j]);
        }
        // global max across the 4 lanes (all sources active).
        {
            const float m0 = __shfl(mx, 0), m1 = __shfl(mx, 1);
            const float m2 = __shfl(mx, 2), m3 = __shfl(mx, 3);
            mx = fmaxf(fmaxf(m0, m1), fmaxf(m2, m3));
        }
        #pragma unroll
        for (int j = 0; j < 4; ++j) row[j] -= mx;
        #pragma unroll
        for (int i = 0; i < 4; ++i) col[i] = res_logits[i * 4 + l] * (1.0f / TAU) - mx;

        const float logm = -logf((float)NSTREAMS);
        float u_l = 0.f, v_l = 0.f;
        float u_all[4], v_all[4] = {0.f, 0.f, 0.f, 0.f};

        for (int it = 0; it < SINKHORN_ITERS; ++it) {
            // u[l] = logm - lse_j(row[j] + v[j])   (serial in-order, matches ref)
            float m = -INFINITY;
            #pragma unroll
            for (int j = 0; j < 4; ++j) m = fmaxf(m, row[j] + v_all[j]);
            float s = 0.f;
            #pragma unroll
            for (int j = 0; j < 4; ++j) s += expf(row[j] + v_all[j] - m);
            u_l = logm - (m + logf(s));
            u_all[0] = __shfl(u_l, 0); u_all[1] = __shfl(u_l, 1);
            u_all[2] = __shfl(u_l, 2); u_all[3] = __shfl(u_l, 3);

            // v[l] = logm - lse_i(col[i] + u[i])
            m = -INFINITY;
            #pragma unroll
            for (int i = 0; i < 4; ++i) m = fmaxf(m, col[i] + u_all[i]);
            s = 0.f;
            #pragma unroll
            for (int i = 0; i < 4; ++i) s += expf(col[i] + u_all[i] - m);
            v_l = logm - (m + logf(s));
            v_all[0] = __shfl(v_l, 0); v_all[1] = __shfl(v_l, 1);
            v_all[2] = __shfl(v_l, 2); v_all[3] = __shfl(v_l, 3);
        }
        // lane l writes column l: h_res[i][l] = exp(scaled[i][l] + u[i] + v[l]) * S
        #pragma unroll
        for (int i = 0; i < 4; ++i)
            sc[i * 4 + l] = expf(col[i] + u_all[i] + v_l) * (float)NSTREAMS;
    } else if (tid == 64) {
        // wave 1: the two 4-way softmaxes, concurrent with wave 0's Sinkhorn.
        {
            float m = -INFINITY;
            #pragma unroll
            for (int k = 0; k < 4; ++k) m = fmaxf(m, pre_logits[k]);
            float e[4], s = 0.f;
            #pragma unroll
            for (int k = 0; k < 4; ++k) { e[k] = expf(pre_logits[k] - m); s += e[k]; }
            #pragma unroll
            for (int k = 0; k < 4; ++k) sc[16 + k] = e[k] / s;
        }
        {
            float m = -INFINITY;
            #pragma unroll
            for (int k = 0; k < 4; ++k) m = fmaxf(m, post_logits[k]);
            float e[4], s = 0.f;
            #pragma unroll
            for (int k = 0; k < 4; ++k) { e[k] = expf(post_logits[k] - m); s += e[k]; }
            #pragma unroll
            for (int k = 0; k < 4; ++k) sc[20 + k] = e[k] / s;
        }
    }
    __syncthreads();

    float hres[16], hpre[4], hpost[4];
    #pragma unroll
    for (int k = 0; k < 16; ++k) hres[k] = sc[k];
    #pragma unroll
    for (int k = 0; k < 4; ++k) { hpre[k] = sc[16 + k]; hpost[k] = sc[20 + k]; }

    // ---- streaming mix: r fixed per thread, loop b = 0..7 at compile time ----
    const int r = blockIdx.x * blockDim.x + tid;   // 0 .. (1<<19)-1, exact cover

    #pragma unroll 2
    for (int b = 0; b < BATCH; ++b) {
        const int base = (b << 2) << N4_SHIFT;     // stream j at base + (j<<19) + r

        const f32x4 x0 = in[base + (0 << N4_SHIFT) + r];
        const f32x4 x1 = in[base + (1 << N4_SHIFT) + r];
        const f32x4 x2 = in[base + (2 << N4_SHIFT) + r];
        const f32x4 x3 = in[base + (3 << N4_SHIFT) + r];

        // branch_input = sum_j h_pre[j] * x_j
        f32x4 bi = hpre[0] * x0;
        bi += hpre[1] * x1;
        bi += hpre[2] * x2;
        bi += hpre[3] * x3;

        #pragma unroll
        for (int i = 0; i < 4; ++i) {
            f32x4 o = hres[i * 4 + 0] * x0;
            o += hres[i * 4 + 1] * x1;
            o += hres[i * 4 + 2] * x2;
            o += hres[i * 4 + 3] * x3;
            o += hpost[i] * bi;
            out[base + (i << N4_SHIFT) + r] = o;
        }
    }
}

extern "C" void kernel_launch(void* const* d_in, const int* in_sizes, int n_in,
                              void* d_out, int out_size, void* d_ws, size_t ws_size,
                              hipStream_t stream) {
    const float* streams     = (const float*)d_in[0];
    const float* h_res_log   = (const float*)d_in[1];
    const float* h_pre_log   = (const float*)d_in[2];
    const float* h_post_log  = (const float*)d_in[3];
    float* out = (float*)d_out;

    // 2048 blocks x 256 threads = 1<<19 threads = one b-slice of float4 items.
    fused_mix_kernel<<<2048, 256, 0, stream>>>(
        (const f32x4*)streams, (f32x4*)out, h_res_log, h_pre_log, h_post_log);
}

// Round 10
// 460.067 us; speedup vs baseline: 1.0062x; 1.0062x over previous
//
#include <hip/hip_runtime.h>
#include <math.h>

// Problem constants (from reference setup_inputs): B_eff=32, T=2048, D=1024, S=4.
#define NSTREAMS 4
#define SINKHORN_ITERS 10
#define TAU 0.05f
#define N4_SHIFT 19        // T*D/4 = 524288 float4 per (b,stream) slice
#define TOTAL_ITEMS (8 << N4_SHIFT)   // 4,194,304 float4 work-items

typedef float f32x4 __attribute__((ext_vector_type(4)));

// ---------------------------------------------------------------------------
// Kernel 1 (1 block, lane 0): Sinkhorn + softmaxes, then FOLD the branch term:
//   M[i][j] = h_res[i][j] + h_post[i] * h_pre[j]
// so the mix kernel is a single 4x4 matrix apply. Writes 16 floats to d_ws.
// ~2-3 us serial; proven neutral vs fusing (R4 vs R6).
// ---------------------------------------------------------------------------
__global__ void coeff_kernel(const float* __restrict__ res_logits,
                             const float* __restrict__ pre_logits,
                             const float* __restrict__ post_logits,
                             float* __restrict__ Mout) {
    if (threadIdx.x != 0 || blockIdx.x != 0) return;

    float scaled[NSTREAMS][NSTREAMS];
    float mx = -INFINITY;
    #pragma unroll
    for (int i = 0; i < NSTREAMS; ++i)
        #pragma unroll
        for (int j = 0; j < NSTREAMS; ++j) {
            float sv = res_logits[i * NSTREAMS + j] * (1.0f / TAU);
            scaled[i][j] = sv;
            mx = fmaxf(mx, sv);
        }
    #pragma unroll
    for (int i = 0; i < NSTREAMS; ++i)
        #pragma unroll
        for (int j = 0; j < NSTREAMS; ++j)
            scaled[i][j] -= mx;

    const float logm = -logf((float)NSTREAMS);
    float uu[NSTREAMS] = {0.f, 0.f, 0.f, 0.f};
    float vv[NSTREAMS] = {0.f, 0.f, 0.f, 0.f};

    for (int it = 0; it < SINKHORN_ITERS; ++it) {
        #pragma unroll
        for (int i = 0; i < NSTREAMS; ++i) {
            float m = -INFINITY;
            #pragma unroll
            for (int j = 0; j < NSTREAMS; ++j) m = fmaxf(m, scaled[i][j] + vv[j]);
            float s = 0.f;
            #pragma unroll
            for (int j = 0; j < NSTREAMS; ++j) s += expf(scaled[i][j] + vv[j] - m);
            uu[i] = logm - (m + logf(s));
        }
        #pragma unroll
        for (int j = 0; j < NSTREAMS; ++j) {
            float m = -INFINITY;
            #pragma unroll
            for (int i = 0; i < NSTREAMS; ++i) m = fmaxf(m, scaled[i][j] + uu[i]);
            float s = 0.f;
            #pragma unroll
            for (int i = 0; i < NSTREAMS; ++i) s += expf(scaled[i][j] + uu[i] - m);
            vv[j] = logm - (m + logf(s));
        }
    }

    float hres[NSTREAMS][NSTREAMS];
    #pragma unroll
    for (int i = 0; i < NSTREAMS; ++i)
        #pragma unroll
        for (int j = 0; j < NSTREAMS; ++j)
            hres[i][j] = expf(scaled[i][j] + uu[i] + vv[j]) * (float)NSTREAMS;

    float hpre[NSTREAMS], hpost[NSTREAMS];
    {
        float m = -INFINITY;
        #pragma unroll
        for (int k = 0; k < NSTREAMS; ++k) m = fmaxf(m, pre_logits[k]);
        float e[NSTREAMS], s = 0.f;
        #pragma unroll
        for (int k = 0; k < NSTREAMS; ++k) { e[k] = expf(pre_logits[k] - m); s += e[k]; }
        #pragma unroll
        for (int k = 0; k < NSTREAMS; ++k) hpre[k] = e[k] / s;
    }
    {
        float m = -INFINITY;
        #pragma unroll
        for (int k = 0; k < NSTREAMS; ++k) m = fmaxf(m, post_logits[k]);
        float e[NSTREAMS], s = 0.f;
        #pragma unroll
        for (int k = 0; k < NSTREAMS; ++k) { e[k] = expf(post_logits[k] - m); s += e[k]; }
        #pragma unroll
        for (int k = 0; k < NSTREAMS; ++k) hpost[k] = e[k] / s;
    }

    // Fold: out_i = sum_j (hres[i][j] + hpost[i]*hpre[j]) * x_j
    #pragma unroll
    for (int i = 0; i < NSTREAMS; ++i)
        #pragma unroll
        for (int j = 0; j < NSTREAMS; ++j)
            Mout[i * NSTREAMS + j] = hres[i][j] + hpost[i] * hpre[j];
}

// ---------------------------------------------------------------------------
// Kernel 2: copy-shaped streaming mix. ONE float4-quad per thread, no loop —
// mirrors the 6.3-6.5 TB/s copy/fill recipe (tiny per-thread work, huge grid,
// low VGPR, fire-and-forget stores). Grid 16384 x 256 = 4,194,304 items exact.
// ---------------------------------------------------------------------------
__global__ __launch_bounds__(256) void mix_kernel(const f32x4* __restrict__ in,
                                                  f32x4* __restrict__ out,
                                                  const float* __restrict__ M) {
    // Thread-invariant coefficient loads -> scalar path, K$-cached.
    float m[16];
    #pragma unroll
    for (int k = 0; k < 16; ++k) m[k] = M[k];

    const int p = blockIdx.x * 256 + threadIdx.x;   // 0 .. 4M-1, exact cover
    const int b = p >> N4_SHIFT;
    const int r = p & ((1 << N4_SHIFT) - 1);
    const int base = (b << 2) << N4_SHIFT;          // stream j at base + (j<<19) + r

    const f32x4 x0 = in[base + (0 << N4_SHIFT) + r];
    const f32x4 x1 = in[base + (1 << N4_SHIFT) + r];
    const f32x4 x2 = in[base + (2 << N4_SHIFT) + r];
    const f32x4 x3 = in[base + (3 << N4_SHIFT) + r];

    #pragma unroll
    for (int i = 0; i < 4; ++i) {
        f32x4 o = m[i * 4 + 0] * x0;
        o += m[i * 4 + 1] * x1;
        o += m[i * 4 + 2] * x2;
        o += m[i * 4 + 3] * x3;
        out[base + (i << N4_SHIFT) + r] = o;
    }
}

extern "C" void kernel_launch(void* const* d_in, const int* in_sizes, int n_in,
                              void* d_out, int out_size, void* d_ws, size_t ws_size,
                              hipStream_t stream) {
    const float* streams     = (const float*)d_in[0];
    const float* h_res_log   = (const float*)d_in[1];
    const float* h_pre_log   = (const float*)d_in[2];
    const float* h_post_log  = (const float*)d_in[3];
    float* out = (float*)d_out;
    float* M   = (float*)d_ws;   // 16 floats

    coeff_kernel<<<1, 64, 0, stream>>>(h_res_log, h_pre_log, h_post_log, M);

    // One float4-quad per thread: 16384 blocks x 256 threads = 4M items.
    mix_kernel<<<TOTAL_ITEMS / 256, 256, 0, stream>>>(
        (const f32x4*)streams, (f32x4*)out, M);
}

// Round 12
// 456.636 us; speedup vs baseline: 1.0138x; 1.0075x over previous
//
#include <hip/hip_runtime.h>
#include <math.h>

// Problem constants (from reference setup_inputs): B_eff=32, T=2048, D=1024, S=4.
#define NSTREAMS 4
#define SINKHORN_ITERS 10
#define TAU 0.05f
#define N4_SHIFT 19        // T*D/4 = 524288 float4 per (b,stream) slice

typedef float f32x4 __attribute__((ext_vector_type(4)));

// ---------------------------------------------------------------------------
// Kernel 1 (1 block, lane 0): Sinkhorn + softmaxes, folded into one matrix:
//   M[i][j] = h_res[i][j] + h_post[i] * h_pre[j]
// 16 floats to d_ws. ~2-3 us, proven off-critical-path (R4 vs R6 neutral).
// ---------------------------------------------------------------------------
__global__ void coeff_kernel(const float* __restrict__ res_logits,
                             const float* __restrict__ pre_logits,
                             const float* __restrict__ post_logits,
                             float* __restrict__ Mout) {
    if (threadIdx.x != 0 || blockIdx.x != 0) return;

    float scaled[NSTREAMS][NSTREAMS];
    float mx = -INFINITY;
    #pragma unroll
    for (int i = 0; i < NSTREAMS; ++i)
        #pragma unroll
        for (int j = 0; j < NSTREAMS; ++j) {
            float sv = res_logits[i * NSTREAMS + j] * (1.0f / TAU);
            scaled[i][j] = sv;
            mx = fmaxf(mx, sv);
        }
    #pragma unroll
    for (int i = 0; i < NSTREAMS; ++i)
        #pragma unroll
        for (int j = 0; j < NSTREAMS; ++j)
            scaled[i][j] -= mx;

    const float logm = -logf((float)NSTREAMS);
    float uu[NSTREAMS] = {0.f, 0.f, 0.f, 0.f};
    float vv[NSTREAMS] = {0.f, 0.f, 0.f, 0.f};

    for (int it = 0; it < SINKHORN_ITERS; ++it) {
        #pragma unroll
        for (int i = 0; i < NSTREAMS; ++i) {
            float m = -INFINITY;
            #pragma unroll
            for (int j = 0; j < NSTREAMS; ++j) m = fmaxf(m, scaled[i][j] + vv[j]);
            float s = 0.f;
            #pragma unroll
            for (int j = 0; j < NSTREAMS; ++j) s += expf(scaled[i][j] + vv[j] - m);
            uu[i] = logm - (m + logf(s));
        }
        #pragma unroll
        for (int j = 0; j < NSTREAMS; ++j) {
            float m = -INFINITY;
            #pragma unroll
            for (int i = 0; i < NSTREAMS; ++i) m = fmaxf(m, scaled[i][j] + uu[i]);
            float s = 0.f;
            #pragma unroll
            for (int i = 0; i < NSTREAMS; ++i) s += expf(scaled[i][j] + uu[i] - m);
            vv[j] = logm - (m + logf(s));
        }
    }

    float hres[NSTREAMS][NSTREAMS];
    #pragma unroll
    for (int i = 0; i < NSTREAMS; ++i)
        #pragma unroll
        for (int j = 0; j < NSTREAMS; ++j)
            hres[i][j] = expf(scaled[i][j] + uu[i] + vv[j]) * (float)NSTREAMS;

    float hpre[NSTREAMS], hpost[NSTREAMS];
    {
        float m = -INFINITY;
        #pragma unroll
        for (int k = 0; k < NSTREAMS; ++k) m = fmaxf(m, pre_logits[k]);
        float e[NSTREAMS], s = 0.f;
        #pragma unroll
        for (int k = 0; k < NSTREAMS; ++k) { e[k] = expf(pre_logits[k] - m); s += e[k]; }
        #pragma unroll
        for (int k = 0; k < NSTREAMS; ++k) hpre[k] = e[k] / s;
    }
    {
        float m = -INFINITY;
        #pragma unroll
        for (int k = 0; k < NSTREAMS; ++k) m = fmaxf(m, post_logits[k]);
        float e[NSTREAMS], s = 0.f;
        #pragma unroll
        for (int k = 0; k < NSTREAMS; ++k) { e[k] = expf(post_logits[k] - m); s += e[k]; }
        #pragma unroll
        for (int k = 0; k < NSTREAMS; ++k) hpost[k] = e[k] / s;
    }

    #pragma unroll
    for (int i = 0; i < NSTREAMS; ++i)
        #pragma unroll
        for (int j = 0; j < NSTREAMS; ++j)
            Mout[i * NSTREAMS + j] = hres[i][j] + hpost[i] * hpre[j];
}

// ---------------------------------------------------------------------------
// Kernel 2: batched-2 copy-shaped mix. Each thread owns TWO r-positions
// (r0 = blk*512 + tid, r1 = r0 + 256; both inside one b-slice since 512
// divides 524288). Issue all 8 loads back-to-back (independent), one wait
// region, compute, then 8 independent back-to-back stores (fill-like burst).
// Discriminator: wait-point density vs MALL-backlog conveyor.
// ---------------------------------------------------------------------------
__global__ __launch_bounds__(256) void mix_kernel(const f32x4* __restrict__ in,
                                                  f32x4* __restrict__ out,
                                                  const float* __restrict__ M) {
    float m[16];
    #pragma unroll
    for (int k = 0; k < 16; ++k) m[k] = M[k];

    const int p0 = blockIdx.x * 512 + threadIdx.x;   // item 0
    const int b = p0 >> N4_SHIFT;                    // same b for p0 and p0+256
    const int r0 = p0 & ((1 << N4_SHIFT) - 1);
    const int base = (b << 2) << N4_SHIFT;

    // 8 independent loads, issued back-to-back.
    const f32x4 a0 = in[base + (0 << N4_SHIFT) + r0];
    const f32x4 a1 = in[base + (1 << N4_SHIFT) + r0];
    const f32x4 a2 = in[base + (2 << N4_SHIFT) + r0];
    const f32x4 a3 = in[base + (3 << N4_SHIFT) + r0];
    const f32x4 c0 = in[base + (0 << N4_SHIFT) + r0 + 256];
    const f32x4 c1 = in[base + (1 << N4_SHIFT) + r0 + 256];
    const f32x4 c2 = in[base + (2 << N4_SHIFT) + r0 + 256];
    const f32x4 c3 = in[base + (3 << N4_SHIFT) + r0 + 256];

    f32x4 oa[4], oc[4];
    #pragma unroll
    for (int i = 0; i < 4; ++i) {
        f32x4 o = m[i * 4 + 0] * a0;
        o += m[i * 4 + 1] * a1;
        o += m[i * 4 + 2] * a2;
        o += m[i * 4 + 3] * a3;
        oa[i] = o;
        f32x4 q = m[i * 4 + 0] * c0;
        q += m[i * 4 + 1] * c1;
        q += m[i * 4 + 2] * c2;
        q += m[i * 4 + 3] * c3;
        oc[i] = q;
    }

    // 8 independent stores, back-to-back (fill-like burst).
    #pragma unroll
    for (int i = 0; i < 4; ++i)
        out[base + (i << N4_SHIFT) + r0] = oa[i];
    #pragma unroll
    for (int i = 0; i < 4; ++i)
        out[base + (i << N4_SHIFT) + r0 + 256] = oc[i];
}

extern "C" void kernel_launch(void* const* d_in, const int* in_sizes, int n_in,
                              void* d_out, int out_size, void* d_ws, size_t ws_size,
                              hipStream_t stream) {
    const float* streams     = (const float*)d_in[0];
    const float* h_res_log   = (const float*)d_in[1];
    const float* h_pre_log   = (const float*)d_in[2];
    const float* h_post_log  = (const float*)d_in[3];
    float* out = (float*)d_out;
    float* M   = (float*)d_ws;   // 16 floats

    coeff_kernel<<<1, 64, 0, stream>>>(h_res_log, h_pre_log, h_post_log, M);

    // 8192 blocks x 256 threads x 2 items = 4,194,304 float4 items, exact.
    mix_kernel<<<8192, 256, 0, stream>>>((const f32x4*)streams, (f32x4*)out, M);
}